// Round 6
// baseline (489.897 us; speedup 1.0000x reference)
//
#include <hip/hip_runtime.h>
#include <hip/hip_bf16.h>

// Mamba2 forward, MI355X (gfx950).
// casts -> GEMM1 (256^2 8-wave, BK=64, m201-style 4-quadrant-phase pipeline)
// -> conv+silu (bf16) -> dt -> SSD pass A (local Y + chunk states)
// -> SSD pass B (sequential chunk-state scan, tiny)
// -> SSD pass C (inter-chunk Y) -> gate+RMSNorm -> GEMM2 (128x256, 256 blocks).
// States (67MB bf16) live in d_out scratch (33.5MB) + ws region shared with
// the cast buffers (dead after GEMM1). ws NEED = 148.37MB (<= proven 149.4MB).
// R6: GEMM1 = faithful m201 fine-interleave port: per K=64 tile, 4 phases of
// {ds_read quadrant frags | stage one 16KB chunk | bar | lgkmcnt(0) | setprio
// 16 MFMA | bar}, vmcnt(0) only at P3 (loads get >=1 phase of slack).

typedef __attribute__((ext_vector_type(8))) short bf16x8;
typedef __attribute__((ext_vector_type(4))) float f32x4;

static constexpr int B_ = 4;
static constexpr int L_ = 2048;
static constexpr int NROWS = B_ * L_;
static constexpr int DMODEL = 1024;
static constexpr int DINNER = 2048;
static constexpr int NH = 32;
static constexpr int DSTATE = 128;
static constexpr int CONVDIM = DINNER + 2 * DSTATE;          // 2304
static constexpr int DINPROJ = 2 * DINNER + 2 * DSTATE + NH; // 4384
static constexpr int Q_ = 64;
static constexpr int NCHUNK = L_ / Q_;                        // 32

__device__ __forceinline__ unsigned pk_bf16(float a, float b) {
  unsigned ua = __builtin_bit_cast(unsigned, a);
  unsigned ub = __builtin_bit_cast(unsigned, b);
  ua = (ua + 0x7FFFu + ((ua >> 16) & 1u)) >> 16;
  ub = (ub + 0x7FFFu + ((ub >> 16) & 1u)) >> 16;
  return (ua & 0xFFFFu) | (ub << 16);
}
__device__ __forceinline__ unsigned short bf16_of(float a) {
  unsigned ua = __builtin_bit_cast(unsigned, a);
  return (unsigned short)((ua + 0x7FFFu + ((ua >> 16) & 1u)) >> 16);
}
__device__ __forceinline__ float f_of_bf16(unsigned short s) {
  return __builtin_bit_cast(float, (unsigned)s << 16);
}
__device__ __forceinline__ unsigned short* state_slot(unsigned short* lo,
                                                      unsigned short* hi,
                                                      int bh, int c) {
  int i = bh * NCHUNK + c;
  return (i < 2048) ? lo + (size_t)i * 8192 : hi + (size_t)(i - 2048) * 8192;
}

// fp32 -> bf16, 4 elems/thread, n divisible by 1024.
__global__ __launch_bounds__(256) void cast4_kernel(const float* __restrict__ in,
                                                    unsigned short* __restrict__ out) {
  int i = blockIdx.x * 256 + threadIdx.x;
  float4 v = ((const float4*)in)[i];
  ((uint2*)out)[i] = make_uint2(pk_bf16(v.x, v.y), pk_bf16(v.z, v.w));
}

#define WAITVM(N) asm volatile("s_waitcnt vmcnt(" #N ")" ::: "memory")

// ---------------------------------------------------------------------------
// GEMM1: 256x256 tile, BK=64, 8 waves (2Mx4N), per-wave C = 128x64 acc[8][4].
// LDS: 2 bufs x 4 chunks x [128 rows][64 K] bf16 = 64KB. Chunk slots:
// 0=Alo(rows 0-127) 1=Blo 2=Bhi 3=Ahi. 16B-granule XOR swizzle phys=k^(row&7):
// staged via pre-swizzled global source (linear LDS dest, rule #21), read with
// the same XOR. Per K-tile t, 4 quadrant phases (hi,hj): P0=(0,0) reads
// A(h0)8+B(h0)4, stages Alo(t+1); P1=(0,1) reads B(h1)4, stages Ahi(t+1);
// P2=(1,1) reads A(h1)8 (af WAR after P1 use), stages Blo+Bhi(t+1);
// P3=(1,0) reads none, vmcnt(0) [all t+1 loads >=1 phase old -> ~no stall].
// Each phase: reads|stage|s_barrier|lgkmcnt(0)+sched_barrier|setprio 16 MFMA|
// [vmcnt]|s_barrier|sched_barrier. Ring safety: stage into buf (t+1)&1
// clobbers tile t-1 chunks whose last reads drained >=2 phases earlier behind
// barriers; vmcnt(0)+BAR at P3 publishes tile t+1 before its P0 reads.
// N predicated on store (B rows < NT*256 readable via caller padding).
// ---------------------------------------------------------------------------
template <bool C_BF16>
__global__ __launch_bounds__(512, 1) void gemm8p_kernel(
    const unsigned short* __restrict__ A, const unsigned short* __restrict__ Bw,
    void* __restrict__ Cp, int N, int K, int lda, int ldb, int ldc) {
  __shared__ unsigned short sAB[2 * 4 * 128 * 64];  // 64KB
  const int tid = threadIdx.x;
  const int w = tid >> 6;
  const int lane = tid & 63;
  const int quad = lane >> 4;
  const int r15 = lane & 15;
  const int wm = w >> 2;  // 0..1 M half
  const int wn = w & 3;   // 0..3 64-col quarter

  // 2-level XCD-aware mapping (bijective; gridDim.y % 8 == 0).
  const int NT = gridDim.x;
  const int orig = blockIdx.y * NT + blockIdx.x;
  const int xcd = orig & 7;
  const int loc = orig >> 3;
  const int mPerX = gridDim.y >> 3;
  const int m0 = (xcd * mPerX + (loc % mPerX)) * 256;
  const int n0 = (loc / mPerX) * 256;

  // staging: 512 thr cover 64 rows x 8 phys chunks per gload (8KB); 2 gloads
  // per 16KB chunk (rows +0 / +64). Source col pre-swizzled by row&7.
  const int srow = tid >> 3;                     // 0..63
  const int px = ((tid & 7) ^ (srow & 7)) * 8;   // swizzled source col chunk
  const unsigned short* gA = A + (size_t)(m0 + srow) * lda + px;
  const unsigned short* gB = Bw + (size_t)(n0 + srow) * ldb + px;
  auto ldsAB = (__attribute__((address_space(3))) unsigned short*)sAB;
  const int dst = w * 512;  // shorts; HW adds lane*16B

  auto stageA = [&](int buf, int hi, int kt) {
    const unsigned short* s0 = gA + (size_t)(hi * 128) * lda + (size_t)kt * 64;
    int d = buf + (hi ? 3 : 0) * 8192 + dst;
    __builtin_amdgcn_global_load_lds(
        (const __attribute__((address_space(1))) void*)s0,
        (__attribute__((address_space(3))) void*)(ldsAB + d), 16, 0, 0);
    __builtin_amdgcn_global_load_lds(
        (const __attribute__((address_space(1))) void*)(s0 + (size_t)64 * lda),
        (__attribute__((address_space(3))) void*)(ldsAB + d + 4096), 16, 0, 0);
  };
  auto stageB = [&](int buf, int hi, int kt) {
    const unsigned short* s0 = gB + (size_t)(hi * 128) * ldb + (size_t)kt * 64;
    int d = buf + (hi ? 2 : 1) * 8192 + dst;
    __builtin_amdgcn_global_load_lds(
        (const __attribute__((address_space(1))) void*)s0,
        (__attribute__((address_space(3))) void*)(ldsAB + d), 16, 0, 0);
    __builtin_amdgcn_global_load_lds(
        (const __attribute__((address_space(1))) void*)(s0 + (size_t)64 * ldb),
        (__attribute__((address_space(3))) void*)(ldsAB + d + 4096), 16, 0, 0);
  };

  // read-side: logical chunk quad (ks=0) / quad+4 (ks=1); row&7 == r15&7.
  const int px0 = (quad ^ (r15 & 7)) * 8;
  const int px1 = ((quad + 4) ^ (r15 & 7)) * 8;
  const int aslot = (wm ? 3 : 0) * 8192;
  const int bslot = ((wn >> 1) ? 2 : 1) * 8192;
  const int arow0 = r15 * 64;
  const int brow0 = ((wn & 1) * 64 + r15) * 64;

  f32x4 acc[8][4];
#pragma unroll
  for (int i = 0; i < 8; ++i)
#pragma unroll
    for (int j = 0; j < 4; ++j) acc[i][j] = f32x4{0.f, 0.f, 0.f, 0.f};

  bf16x8 af[4][2], bfr[2][2][2];

#define READ_A(BUF, HI)                                                         \
  _Pragma("unroll") for (int ii = 0; ii < 4; ++ii) {                            \
    int ba = (BUF) + aslot + arow0 + (HI) * 4096 + ii * 1024;                   \
    af[ii][0] = *(const bf16x8*)&sAB[ba + px0];                                 \
    af[ii][1] = *(const bf16x8*)&sAB[ba + px1];                                 \
  }
#define READ_B(BUF, HJ)                                                         \
  _Pragma("unroll") for (int jj = 0; jj < 2; ++jj) {                            \
    int bb = (BUF) + bslot + brow0 + (HJ) * 2048 + jj * 1024;                   \
    bfr[HJ][jj][0] = *(const bf16x8*)&sAB[bb + px0];                            \
    bfr[HJ][jj][1] = *(const bf16x8*)&sAB[bb + px1];                            \
  }
#define MFMA_Q(HI, HJ)                                                          \
  _Pragma("unroll") for (int ii = 0; ii < 4; ++ii)                              \
    _Pragma("unroll") for (int jj = 0; jj < 2; ++jj) {                          \
      acc[(HI) * 4 + ii][(HJ) * 2 + jj] = __builtin_amdgcn_mfma_f32_16x16x32_bf16( \
          af[ii][0], bfr[HJ][jj][0], acc[(HI) * 4 + ii][(HJ) * 2 + jj], 0, 0, 0);  \
      acc[(HI) * 4 + ii][(HJ) * 2 + jj] = __builtin_amdgcn_mfma_f32_16x16x32_bf16( \
          af[ii][1], bfr[HJ][jj][1], acc[(HI) * 4 + ii][(HJ) * 2 + jj], 0, 0, 0);  \
    }
#define PHASE(READS, STAGES, MFMAQ, VMW)                                        \
  {                                                                             \
    READS;                                                                      \
    STAGES;                                                                     \
    __builtin_amdgcn_s_barrier();                                               \
    asm volatile("s_waitcnt lgkmcnt(0)" ::: "memory");                          \
    __builtin_amdgcn_sched_barrier(0);                                          \
    __builtin_amdgcn_s_setprio(1);                                              \
    MFMAQ;                                                                      \
    __builtin_amdgcn_s_setprio(0);                                              \
    VMW;                                                                        \
    __builtin_amdgcn_s_barrier();                                               \
    __builtin_amdgcn_sched_barrier(0);                                          \
  }

  const int nt = K >> 6;
  // prologue: tile 0 fully staged + retired.
  stageA(0, 0, 0);
  stageA(0, 1, 0);
  stageB(0, 0, 0);
  stageB(0, 1, 0);
  WAITVM(0);
  __builtin_amdgcn_s_barrier();
  __builtin_amdgcn_sched_barrier(0);

  for (int t = 0; t < nt; ++t) {
    const int buf = (t & 1) * 32768;
    const int nb = ((t + 1) & 1) * 32768;
    const bool more = (t + 1 < nt);
    const int k1 = t + 1;
    PHASE(READ_A(buf, 0); READ_B(buf, 0),
          if (more) stageA(nb, 0, k1),
          MFMA_Q(0, 0), (void)0);
    PHASE(READ_B(buf, 1),
          if (more) stageA(nb, 1, k1),
          MFMA_Q(0, 1), (void)0);
    PHASE(READ_A(buf, 1),
          if (more) { stageB(nb, 0, k1); stageB(nb, 1, k1); },
          MFMA_Q(1, 1), (void)0);
    PHASE((void)0, (void)0, MFMA_Q(1, 0), WAITVM(0));
  }
#undef PHASE
#undef MFMA_Q
#undef READ_B
#undef READ_A

  const int rq = quad * 4;
#pragma unroll
  for (int i = 0; i < 8; ++i) {
#pragma unroll
    for (int j = 0; j < 4; ++j) {
      int gcol = n0 + wn * 64 + j * 16 + r15;
      if (gcol < N) {
#pragma unroll
        for (int r = 0; r < 4; ++r) {
          size_t grow = (size_t)(m0 + wm * 128 + i * 16 + rq + r);
          if constexpr (C_BF16)
            ((unsigned short*)Cp)[grow * (size_t)ldc + gcol] = bf16_of(acc[i][j][r]);
          else
            ((float*)Cp)[grow * (size_t)ldc + gcol] = acc[i][j][r];
        }
      }
    }
  }
}

// ---------------------------------------------------------------------------
// R5's BMx256 2-barrier kernel — retained for GEMM2 (BM=128, 256 blocks).
// ---------------------------------------------------------------------------
template <int BM, bool C_BF16>
__global__ __launch_bounds__(512, 1) void gemm256_kernel(
    const unsigned short* __restrict__ A, const unsigned short* __restrict__ Bw,
    void* __restrict__ Cp, int M, int N, int K, int lda, int ldb, int ldc) {
  (void)M;
  constexpr int MI = BM / 32;
  constexpr int TOTROWS = BM + 256;
  constexpr int RPW = TOTROWS / 8;
  constexpr int NLD = RPW / 16;
  __shared__ unsigned short sAB[4 * TOTROWS * 32];
  const int tid = threadIdx.x;
  const int w = tid >> 6;
  const int lane = tid & 63;
  const int quad = lane >> 4;
  const int r15 = lane & 15;

  const int NT = gridDim.x;
  const int orig = blockIdx.y * NT + blockIdx.x;
  const int xcd = orig & 7;
  const int loc = orig >> 3;
  const int mPerX = gridDim.y >> 3;
  const int m0 = (xcd * mPerX + (loc % mPerX)) * BM;
  const int n0 = (loc / mPerX) * 256;

  const int wm = w >> 2;
  const int wn = w & 3;

  const unsigned short* gsrc[NLD];
  int lofs[NLD];
#pragma unroll
  for (int ld = 0; ld < NLD; ++ld) {
    int r16 = w * RPW + ld * 16;
    int row = r16 + (lane >> 2);
    int ca = ((lane & 3) ^ ((row >> 1) & 3)) * 8;
    gsrc[ld] = (r16 < BM) ? A + (size_t)(m0 + row) * lda + ca
                          : Bw + (size_t)(n0 + row - BM) * ldb + ca;
    lofs[ld] = r16 * 32;
  }
  const int nslice = K >> 5;

  f32x4 acc[MI][4];
#pragma unroll
  for (int i = 0; i < MI; ++i)
#pragma unroll
    for (int j = 0; j < 4; ++j) acc[i][j] = f32x4{0.f, 0.f, 0.f, 0.f};

  auto ldsAB = (__attribute__((address_space(3))) unsigned short*)sAB;

  auto stage = [&](int ks) {
    const int so = (ks & 3) * (TOTROWS * 32);
#pragma unroll
    for (int ld = 0; ld < NLD; ++ld)
      __builtin_amdgcn_global_load_lds(
          (const __attribute__((address_space(1))) void*)(gsrc[ld] + (size_t)ks * 32),
          (__attribute__((address_space(3))) void*)(ldsAB + so + lofs[ld]), 16, 0, 0);
  };

  const int kx = (quad ^ ((r15 >> 1) & 3)) * 8;

  bf16x8 af[MI], bf[4];

#define READF(S)                                                                \
  {                                                                             \
    const int so_ = ((S) & 3) * (TOTROWS * 32);                                 \
    _Pragma("unroll") for (int i = 0; i < MI; ++i)                              \
        af[i] = *(const bf16x8*)&sAB[so_ + (wm * (BM / 2) + i * 16 + r15) * 32 + kx]; \
    _Pragma("unroll") for (int j = 0; j < 4; ++j)                               \
        bf[j] = *(const bf16x8*)&sAB[so_ + (BM + wn * 64 + j * 16 + r15) * 32 + kx];  \
  }
#define MFMAC()                                                                 \
  _Pragma("unroll") for (int i = 0; i < MI; ++i)                                \
      _Pragma("unroll") for (int j = 0; j < 4; ++j)                             \
          acc[i][j] = __builtin_amdgcn_mfma_f32_16x16x32_bf16(af[i], bf[j],     \
                                                              acc[i][j], 0, 0, 0);

#define WVM_STEADY do { if constexpr (NLD == 4) WAITVM(8); else WAITVM(6); } while (0)
#define WVM_TAIL1  do { if constexpr (NLD == 4) WAITVM(4); else WAITVM(3); } while (0)

  stage(0);
  stage(1);
  stage(2);
  WVM_STEADY;
  __builtin_amdgcn_s_barrier();
  __builtin_amdgcn_sched_barrier(0);

#define GITER(STAGE_STMT, WVM_STMT)                                             \
  {                                                                             \
    READF(s);                                                                   \
    STAGE_STMT;                                                                 \
    __builtin_amdgcn_s_barrier();                                               \
    asm volatile("s_waitcnt lgkmcnt(0)" ::: "memory");                          \
    __builtin_amdgcn_sched_barrier(0);                                          \
    __builtin_amdgcn_s_setprio(1);                                              \
    MFMAC();                                                                    \
    __builtin_amdgcn_s_setprio(0);                                              \
    WVM_STMT;                                                                   \
    __builtin_amdgcn_s_barrier();                                               \
    __builtin_amdgcn_sched_barrier(0);                                          \
  }

  int s = 0;
  for (; s < nslice - 3; ++s) GITER(stage(s + 3), WVM_STEADY);
  GITER((void)0, WVM_TAIL1);
  ++s;
  GITER((void)0, WAITVM(0));
  ++s;
  GITER((void)0, WAITVM(0));
#undef GITER
#undef WVM_STEADY
#undef WVM_TAIL1
#undef MFMAC
#undef READF

  const int rq = quad * 4;
#pragma unroll
  for (int i = 0; i < MI; ++i) {
#pragma unroll
    for (int j = 0; j < 4; ++j) {
      int gcol = n0 + wn * 64 + j * 16 + r15;
      if (gcol < N) {
#pragma unroll
        for (int r = 0; r < 4; ++r) {
          size_t grow = (size_t)(m0 + wm * (BM / 2) + i * 16 + rq + r);
          if constexpr (C_BF16)
            ((unsigned short*)Cp)[grow * (size_t)ldc + gcol] = bf16_of(acc[i][j][r]);
          else
            ((float*)Cp)[grow * (size_t)ldc + gcol] = acc[i][j][r];
        }
      }
    }
  }
}

// conv(D_CONV=4) + bias + SiLU; bf16 in (zxb cols [2048,4352)), bf16 out.
__global__ __launch_bounds__(256) void conv_kernel(const unsigned short* __restrict__ zx,
                                                   const float* __restrict__ conv_w,
                                                   const float* __restrict__ conv_b,
                                                   unsigned short* __restrict__ xbc) {
  int c = blockIdx.x * 256 + threadIdx.x;  // 9*256 == CONVDIM
  int row = blockIdx.y;
  int l = row & (L_ - 1);
  float acc = conv_b[c];
#pragma unroll
  for (int k = 0; k < 4; ++k) {
    int ll = l + k - 3;
    if (ll >= 0)
      acc = fmaf(f_of_bf16(zx[(size_t)(row + k - 3) * DINPROJ + DINNER + c]),
                 conv_w[c * 4 + k], acc);
  }
  acc = acc / (1.f + __expf(-acc));
  xbc[(size_t)row * CONVDIM + c] = bf16_of(acc);
}

__global__ __launch_bounds__(256) void dt_kernel(const unsigned short* __restrict__ zx,
                                                 const float* __restrict__ dt_bias,
                                                 float* __restrict__ dtv) {
  int i = blockIdx.x * 256 + threadIdx.x;
  int hh = i & (NH - 1);
  int row = i >> 5;
  float x = f_of_bf16(zx[(size_t)row * DINPROJ + DINNER + CONVDIM + hh]) + dt_bias[hh];
  dtv[i] = (x > 20.f) ? x : log1pf(__expf(x));
}

// ---- SSD pass A: per (b,chunk,head) block. Local Y (+D*x) in place over the
// x-region of xbc; chunk state S_c -> state slot (bf16 [p][n], 64x128).
__global__ __launch_bounds__(256) void ssd_passA(unsigned short* __restrict__ xbc,
                                                 const float* __restrict__ dtv,
                                                 const float* __restrict__ A_log,
                                                 const float* __restrict__ Dvec,
                                                 unsigned short* __restrict__ st_lo,
                                                 unsigned short* __restrict__ st_hi) {
  const int bid = blockIdx.x;          // ((b*32 + c)*32 + h)
  const int h = bid & 31;
  const int c = (bid >> 5) & 31;
  const int b = bid >> 10;
  const int bh = b * 32 + h;
  const int tid = threadIdx.x;
  const int w = tid >> 6;
  const int lane = tid & 63;
  const int quad = lane >> 4;
  const int c15 = lane & 15;

  __shared__ unsigned short sXt[64 * 72];   // X^T [p][t]
  __shared__ unsigned short sBq[64 * 136];  // B [s][n] stride 136; S~ alias stride 72
  __shared__ unsigned short sCB[128 * 72];  // C [t][n] stride 136 / BtT [n][s] stride 72
  __shared__ float sdt[64], scs[64], sg[64];

  const float A = -__expf(A_log[h]);
  const float Dh = Dvec[h];
  const int r0 = b * L_ + c * Q_;

  if (w == 0) {
    float v = dtv[(size_t)(r0 + lane) * NH + h];
    sdt[lane] = v;
    float s = v;
#pragma unroll
    for (int off = 1; off < 64; off <<= 1) {
      float t = __shfl_up(s, off, 64);
      if (lane >= off) s += t;
    }
    scs[lane] = s;
    float T = __shfl(s, 63, 64);
    sg[lane] = __expf(A * (T - s)) * v;
  }
  for (int e = tid; e < 512; e += 256) {   // Xt transpose (conflict-free b16 writes)
    int t = e & 63, pb = e >> 6;
    uint4 v = *(const uint4*)&xbc[(size_t)(r0 + t) * CONVDIM + h * 64 + pb * 8];
    const unsigned short* sv = (const unsigned short*)&v;
#pragma unroll
    for (int j = 0; j < 8; ++j) sXt[(pb * 8 + j) * 72 + t] = sv[j];
  }
  for (int e = tid; e < 1024; e += 256) {  // B, C coalesced dwordx4
    int s = e >> 4, ch = e & 15;
    size_t roff = (size_t)(r0 + s) * CONVDIM + DINNER;
    *(uint4*)&sBq[s * 136 + ch * 8] = *(const uint4*)&xbc[roff + ch * 8];
    *(uint4*)&sCB[s * 136 + ch * 8] = *(const uint4*)&xbc[roff + DSTATE + ch * 8];
  }
  __syncthreads();  // B1

  const int wt = w >> 1, wx = w & 1;
  // S = C @ B^T (K=128)
  f32x4 sacc[2][2];
#pragma unroll
  for (int i = 0; i < 2; ++i)
#pragma unroll
    for (int j = 0; j < 2; ++j) sacc[i][j] = f32x4{0.f, 0.f, 0.f, 0.f};
#pragma unroll
  for (int kk = 0; kk < 4; ++kk) {
    int k8 = quad * 8 + kk * 32;
    bf16x8 a0 = *(const bf16x8*)&sCB[(wt * 32 + c15) * 136 + k8];
    bf16x8 a1 = *(const bf16x8*)&sCB[(wt * 32 + 16 + c15) * 136 + k8];
    bf16x8 b0 = *(const bf16x8*)&sBq[(wx * 32 + c15) * 136 + k8];
    bf16x8 b1 = *(const bf16x8*)&sBq[(wx * 32 + 16 + c15) * 136 + k8];
    sacc[0][0] = __builtin_amdgcn_mfma_f32_16x16x32_bf16(a0, b0, sacc[0][0], 0, 0, 0);
    sacc[0][1] = __builtin_amdgcn_mfma_f32_16x16x32_bf16(a0, b1, sacc[0][1], 0, 0, 0);
    sacc[1][0] = __builtin_amdgcn_mfma_f32_16x16x32_bf16(a1, b0, sacc[1][0], 0, 0, 0);
    sacc[1][1] = __builtin_amdgcn_mfma_f32_16x16x32_bf16(a1, b1, sacc[1][1], 0, 0, 0);
  }
  __syncthreads();  // B2

  // S~ into sBq (stride 72); BtT[n][s] = B[s][n]*g_s into sCB (stride 72, global re-read)
#pragma unroll
  for (int i = 0; i < 2; ++i)
#pragma unroll
    for (int j = 0; j < 2; ++j) {
      int scol = wx * 32 + j * 16 + c15;
      float css = scs[scol], dts = sdt[scol];
#pragma unroll
      for (int r = 0; r < 4; ++r) {
        int trow = wt * 32 + i * 16 + quad * 4 + r;
        float v = (scol <= trow) ? sacc[i][j][r] * __expf(A * (scs[trow] - css)) * dts : 0.f;
        sBq[trow * 72 + scol] = bf16_of(v);
      }
    }
  for (int e = tid; e < 1024; e += 256) {
    int s = e & 63, nb = e >> 6;
    uint4 v = *(const uint4*)&xbc[(size_t)(r0 + s) * CONVDIM + DINNER + nb * 8];
    float g = sg[s];
    const unsigned short* sv = (const unsigned short*)&v;
#pragma unroll
    for (int j = 0; j < 8; ++j)
      sCB[(nb * 8 + j) * 72 + s] = bf16_of(f_of_bf16(sv[j]) * g);
  }
  __syncthreads();  // B3

  // Y_local = S~ @ Xt (K=64), += D*x, bf16 in place over x
  f32x4 yacc[2][2];
#pragma unroll
  for (int i = 0; i < 2; ++i)
#pragma unroll
    for (int j = 0; j < 2; ++j) yacc[i][j] = f32x4{0.f, 0.f, 0.f, 0.f};
#pragma unroll
  for (int kk = 0; kk < 2; ++kk) {
    int k8 = quad * 8 + kk * 32;
    bf16x8 a0 = *(const bf16x8*)&sBq[(wt * 32 + c15) * 72 + k8];
    bf16x8 a1 = *(const bf16x8*)&sBq[(wt * 32 + 16 + c15) * 72 + k8];
    bf16x8 b0 = *(const bf16x8*)&sXt[(wx * 32 + c15) * 72 + k8];
    bf16x8 b1 = *(const bf16x8*)&sXt[(wx * 32 + 16 + c15) * 72 + k8];
    yacc[0][0] = __builtin_amdgcn_mfma_f32_16x16x32_bf16(a0, b0, yacc[0][0], 0, 0, 0);
    yacc[0][1] = __builtin_amdgcn_mfma_f32_16x16x32_bf16(a0, b1, yacc[0][1], 0, 0, 0);
    yacc[1][0] = __builtin_amdgcn_mfma_f32_16x16x32_bf16(a1, b0, yacc[1][0], 0, 0, 0);
    yacc[1][1] = __builtin_amdgcn_mfma_f32_16x16x32_bf16(a1, b1, yacc[1][1], 0, 0, 0);
  }
#pragma unroll
  for (int i = 0; i < 2; ++i)
#pragma unroll
    for (int j = 0; j < 2; ++j) {
      int p = wx * 32 + j * 16 + c15;
#pragma unroll
      for (int r = 0; r < 4; ++r) {
        int t = wt * 32 + i * 16 + quad * 4 + r;
        float xv = f_of_bf16(sXt[p * 72 + t]);
        xbc[(size_t)(r0 + t) * CONVDIM + h * 64 + p] = bf16_of(yacc[i][j][r] + Dh * xv);
      }
    }

  // S_c = Xt @ BtT^T (K=64) -> state slot
  f32x4 hacc[2][4];
#pragma unroll
  for (int i = 0; i < 2; ++i)
#pragma unroll
    for (int j = 0; j < 4; ++j) hacc[i][j] = f32x4{0.f, 0.f, 0.f, 0.f};
  const int wp = w >> 1, wn = w & 1;
#pragma unroll
  for (int kk = 0; kk < 2; ++kk) {
    int k8 = quad * 8 + kk * 32;
    bf16x8 a0 = *(const bf16x8*)&sXt[(wp * 32 + c15) * 72 + k8];
    bf16x8 a1 = *(const bf16x8*)&sXt[(wp * 32 + 16 + c15) * 72 + k8];
    bf16x8 bfr[4];
#pragma unroll
    for (int j = 0; j < 4; ++j)
      bfr[j] = *(const bf16x8*)&sCB[(wn * 64 + j * 16 + c15) * 72 + k8];
#pragma unroll
    for (int j = 0; j < 4; ++j) {
      hacc[0][j] = __builtin_amdgcn_mfma_f32_16x16x32_bf16(a0, bfr[j], hacc[0][j], 0, 0, 0);
      hacc[1][j] = __builtin_amdgcn_mfma_f32_16x16x32_bf16(a1, bfr[j], hacc[1][j], 0, 0, 0);
    }
  }
  unsigned short* slot = state_slot(st_lo, st_hi, bh, c);
#pragma unroll
  for (int i = 0; i < 2; ++i)
#pragma unroll
    for (int j = 0; j < 4; ++j)
#pragma unroll
      for (int r = 0; r < 4; ++r) {
        int p = wp * 32 + i * 16 + quad * 4 + r;
        int n = wn * 64 + j * 16 + c15;
        slot[p * 128 + n] = bf16_of(hacc[i][j][r]);
      }
}

// ---- SSD pass B: h_c = d_c*h_{c-1} + S_c; slot overwritten with h_{c-1}.
// grid 256 = (bh, p-half); thread owns 16 contiguous elems.
__global__ __launch_bounds__(256) void ssd_passB(const float* __restrict__ dtv,
                                                 const float* __restrict__ A_log,
                                                 unsigned short* __restrict__ st_lo,
                                                 unsigned short* __restrict__ st_hi) {
  const int bh = blockIdx.x >> 1;
  const int ph = blockIdx.x & 1;
  const int h = bh & 31;
  const int b = bh >> 5;
  const int tid = threadIdx.x;
  __shared__ float sd[NCHUNK];
  const float A = -__expf(A_log[h]);
  if (tid < NCHUNK) {
    float s = 0.f;
    const float* dp = dtv + (size_t)(b * L_ + tid * Q_) * NH + h;
    for (int i = 0; i < Q_; ++i) s += dp[(size_t)i * NH];
    sd[tid] = __expf(A * s);
  }
  __syncthreads();
  float hreg[16];
#pragma unroll
  for (int k = 0; k < 16; ++k) hreg[k] = 0.f;
  const size_t eoff = (size_t)ph * 4096 + (size_t)tid * 16;
  for (int c = 0; c < NCHUNK; ++c) {
    unsigned short* sp = state_slot(st_lo, st_hi, bh, c) + eoff;
    uint4 t0 = ((const uint4*)sp)[0];
    uint4 t1 = ((const uint4*)sp)[1];
    unsigned o[8];
#pragma unroll
    for (int k = 0; k < 8; ++k) o[k] = pk_bf16(hreg[2 * k], hreg[2 * k + 1]);
    ((uint4*)sp)[0] = make_uint4(o[0], o[1], o[2], o[3]);
    ((uint4*)sp)[1] = make_uint4(o[4], o[5], o[6], o[7]);
    float d = sd[c];
    const unsigned short* tv0 = (const unsigned short*)&t0;
    const unsigned short* tv1 = (const unsigned short*)&t1;
#pragma unroll
    for (int k = 0; k < 8; ++k) hreg[k] = d * hreg[k] + f_of_bf16(tv0[k]);
#pragma unroll
    for (int k = 0; k < 8; ++k) hreg[8 + k] = d * hreg[8 + k] + f_of_bf16(tv1[k]);
  }
}

// ---- SSD pass C: Y += exp(A*cs_t) * (C @ h_prev^T); RMW on xbc x-region.
__global__ __launch_bounds__(256) void ssd_passC(unsigned short* __restrict__ xbc,
                                                 const float* __restrict__ dtv,
                                                 const float* __restrict__ A_log,
                                                 const unsigned short* __restrict__ st_lo,
                                                 const unsigned short* __restrict__ st_hi) {
  const int bid = blockIdx.x;
  const int h = bid & 31;
  const int c = (bid >> 5) & 31;
  const int b = bid >> 10;
  const int bh = b * 32 + h;
  const int tid = threadIdx.x;
  const int w = tid >> 6;
  const int lane = tid & 63;
  const int quad = lane >> 4;
  const int c15 = lane & 15;

  __shared__ unsigned short sC[64 * 136];
  __shared__ unsigned short sH[64 * 136];
  __shared__ float srt[64];

  const float A = -__expf(A_log[h]);
  const int r0 = b * L_ + c * Q_;

  if (w == 0) {
    float v = dtv[(size_t)(r0 + lane) * NH + h];
    float s = v;
#pragma unroll
    for (int off = 1; off < 64; off <<= 1) {
      float t = __shfl_up(s, off, 64);
      if (lane >= off) s += t;
    }
    srt[lane] = __expf(A * s);
  }
  const unsigned short* slot =
      state_slot((unsigned short*)st_lo, (unsigned short*)st_hi, bh, c);
  for (int e = tid; e < 1024; e += 256) {
    int s = e >> 4, ch = e & 15;
    *(uint4*)&sC[s * 136 + ch * 8] =
        *(const uint4*)&xbc[(size_t)(r0 + s) * CONVDIM + DINNER + DSTATE + ch * 8];
    *(uint4*)&sH[s * 136 + ch * 8] = *(const uint4*)&slot[s * 128 + ch * 8];
  }
  __syncthreads();

  const int wt = w >> 1, wx = w & 1;
  f32x4 yacc[2][2];
#pragma unroll
  for (int i = 0; i < 2; ++i)
#pragma unroll
    for (int j = 0; j < 2; ++j) yacc[i][j] = f32x4{0.f, 0.f, 0.f, 0.f};
#pragma unroll
  for (int kk = 0; kk < 4; ++kk) {
    int k8 = quad * 8 + kk * 32;
    bf16x8 a0 = *(const bf16x8*)&sC[(wt * 32 + c15) * 136 + k8];
    bf16x8 a1 = *(const bf16x8*)&sC[(wt * 32 + 16 + c15) * 136 + k8];
    bf16x8 b0 = *(const bf16x8*)&sH[(wx * 32 + c15) * 136 + k8];
    bf16x8 b1 = *(const bf16x8*)&sH[(wx * 32 + 16 + c15) * 136 + k8];
    yacc[0][0] = __builtin_amdgcn_mfma_f32_16x16x32_bf16(a0, b0, yacc[0][0], 0, 0, 0);
    yacc[0][1] = __builtin_amdgcn_mfma_f32_16x16x32_bf16(a0, b1, yacc[0][1], 0, 0, 0);
    yacc[1][0] = __builtin_amdgcn_mfma_f32_16x16x32_bf16(a1, b0, yacc[1][0], 0, 0, 0);
    yacc[1][1] = __builtin_amdgcn_mfma_f32_16x16x32_bf16(a1, b1, yacc[1][1], 0, 0, 0);
  }
#pragma unroll
  for (int i = 0; i < 2; ++i)
#pragma unroll
    for (int j = 0; j < 2; ++j) {
      int p = wx * 32 + j * 16 + c15;
#pragma unroll
      for (int r = 0; r < 4; ++r) {
        int t = wt * 32 + i * 16 + quad * 4 + r;
        size_t ga = (size_t)(r0 + t) * CONVDIM + h * 64 + p;
        float v = yacc[i][j][r] * srt[t] + f_of_bf16(xbc[ga]);
        xbc[ga] = bf16_of(v);
      }
    }
}

// gate + RMSNorm; y bf16 from xbc, z bf16 from zxb; out bf16 into z-region.
__global__ __launch_bounds__(256) void norm_kernel(const unsigned short* __restrict__ y_in,
                                                   unsigned short* __restrict__ zxb,
                                                   const float* __restrict__ norm_w) {
  const int row = blockIdx.x;
  const int tid = threadIdx.x;
  float v[8];
  float ss = 0.f;
#pragma unroll
  for (int i = 0; i < 8; ++i) {
    int c = tid + i * 256;
    float yv = f_of_bf16(y_in[(size_t)row * CONVDIM + c]);
    float z = f_of_bf16(zxb[(size_t)row * DINPROJ + c]);
    yv *= z / (1.f + __expf(-z));
    v[i] = yv;
    ss = fmaf(yv, yv, ss);
  }
#pragma unroll
  for (int o = 32; o > 0; o >>= 1) ss += __shfl_down(ss, o, 64);
  __shared__ float sred[4];
  if ((tid & 63) == 0) sred[tid >> 6] = ss;
  __syncthreads();
  float tot = (sred[0] + sred[1]) + (sred[2] + sred[3]);
  float r = rsqrtf(tot * (1.f / (float)DINNER) + 1e-5f);
#pragma unroll
  for (int i = 0; i < 8; ++i) {
    int c = tid + i * 256;
    zxb[(size_t)row * DINPROJ + c] = bf16_of(v[i] * r * norm_w[c]);
  }
}

extern "C" void kernel_launch(void* const* d_in, const int* in_sizes, int n_in,
                              void* d_out, int out_size, void* d_ws, size_t ws_size,
                              hipStream_t stream) {
  (void)in_sizes; (void)n_in; (void)out_size;
  const float* u          = (const float*)d_in[0];
  const float* in_proj_w  = (const float*)d_in[3];
  const float* conv_w     = (const float*)d_in[4];
  const float* conv_b     = (const float*)d_in[5];
  const float* dt_bias    = (const float*)d_in[6];
  const float* A_log      = (const float*)d_in[7];
  const float* Dvec       = (const float*)d_in[8];
  const float* norm_w     = (const float*)d_in[9];
  const float* out_proj_w = (const float*)d_in[10];
  float* out = (float*)d_out;

  constexpr size_t SZ_ZX   = (size_t)NROWS * DINPROJ * 2;   // 71,827,456
  constexpr size_t SZ_XBC  = (size_t)NROWS * CONVDIM * 2;   // 37,748,736
  constexpr size_t SZ_DT   = (size_t)NROWS * NH * 4;        //  1,048,576
  constexpr size_t SZ_SHR  = 33554432;                      // casts, later states-hi
  constexpr size_t SZ_WOUT = (size_t)DMODEL * DINNER * 2;   //  4,194,304
  constexpr size_t NEED = SZ_ZX + SZ_XBC + SZ_DT + SZ_SHR + SZ_WOUT;  // 148,373,504
  if (ws_size < NEED) return;

  char* p = (char*)d_ws;
  unsigned short* zxb  = (unsigned short*)p; p += SZ_ZX;
  unsigned short* xbc  = (unsigned short*)p; p += SZ_XBC;
  float* dtv           = (float*)p;          p += SZ_DT;
  char* shared_reg     = p;                  p += SZ_SHR;
  unsigned short* wout_bf = (unsigned short*)p;

  unsigned short* u_bf   = (unsigned short*)shared_reg;                 // 16.8MB
  unsigned short* win_bf = (unsigned short*)(shared_reg + 16777216);    // 9.0MB + slack
  unsigned short* st_lo  = (unsigned short*)d_out;                      // 2048 slots
  unsigned short* st_hi  = (unsigned short*)shared_reg;                 // 2048 slots

  cast4_kernel<<<(NROWS * DMODEL) / 1024, 256, 0, stream>>>(u, u_bf);
  cast4_kernel<<<(DINPROJ * DMODEL) / 1024, 256, 0, stream>>>(in_proj_w, win_bf);
  cast4_kernel<<<(DMODEL * DINNER) / 1024, 256, 0, stream>>>(out_proj_w, wout_bf);

  // GEMM1: N=4384 via 18 N-tiles of 256 (stores predicated; B-row overreads
  // up to row 4607 stay inside the shared_reg slack past win_bf).
  gemm8p_kernel<true><<<dim3(18, 32), 512, 0, stream>>>(
      u_bf, win_bf, zxb, DINPROJ, DMODEL, DMODEL, DMODEL, DINPROJ);
  conv_kernel<<<dim3(9, NROWS), 256, 0, stream>>>(zxb, conv_w, conv_b, xbc);
  dt_kernel<<<(NROWS * NH) / 256, 256, 0, stream>>>(zxb, dt_bias, dtv);

  ssd_passA<<<B_ * NCHUNK * NH, 256, 0, stream>>>(xbc, dtv, A_log, Dvec, st_lo, st_hi);
  ssd_passB<<<B_ * NH * 2, 256, 0, stream>>>(dtv, A_log, st_lo, st_hi);
  ssd_passC<<<B_ * NCHUNK * NH, 256, 0, stream>>>(xbc, dtv, A_log, st_lo, st_hi);

  norm_kernel<<<NROWS, 256, 0, stream>>>(xbc, zxb, norm_w);
  // GEMM2: BM=128 -> 64 M-tiles x 4 N-tiles = 256 blocks (full chip).
  gemm256_kernel<128, false><<<dim3(4, 64), 512, 0, stream>>>(
      zxb, wout_bf, out, NROWS, DMODEL, DINNER, DINPROJ, DINNER, DMODEL);
}

// Round 9
// 470.622 us; speedup vs baseline: 1.0410x; 1.0410x over previous
//
#include <hip/hip_runtime.h>
#include <hip/hip_bf16.h>

// Mamba2 forward, MI355X (gfx950).
// cast3 (merged) -> GEMM1 (R5-verified 256^2 2-barrier counted ring)
// -> conv+silu+dt (fused) -> SSD pass A -> SSD pass B -> SSD pass C
// -> gate+RMSNorm -> GEMM2 (R5-verified, BM=128, 256 blocks).
// R9: revert GEMMs to the R5 kernel (HW-verified 485us/absmax 0.039; the
// R7/R8 counted-4-phase ring FAILED correctness on HW -> abandoned per m152).
// Pipeline-level wins: 3 casts -> 1 kernel; dt fused into conv. 13->10 launches.

typedef __attribute__((ext_vector_type(8))) short bf16x8;
typedef __attribute__((ext_vector_type(4))) float f32x4;

static constexpr int B_ = 4;
static constexpr int L_ = 2048;
static constexpr int NROWS = B_ * L_;
static constexpr int DMODEL = 1024;
static constexpr int DINNER = 2048;
static constexpr int NH = 32;
static constexpr int DSTATE = 128;
static constexpr int CONVDIM = DINNER + 2 * DSTATE;          // 2304
static constexpr int DINPROJ = 2 * DINNER + 2 * DSTATE + NH; // 4384
static constexpr int Q_ = 64;
static constexpr int NCHUNK = L_ / Q_;                        // 32

__device__ __forceinline__ unsigned pk_bf16(float a, float b) {
  unsigned ua = __builtin_bit_cast(unsigned, a);
  unsigned ub = __builtin_bit_cast(unsigned, b);
  ua = (ua + 0x7FFFu + ((ua >> 16) & 1u)) >> 16;
  ub = (ub + 0x7FFFu + ((ub >> 16) & 1u)) >> 16;
  return (ua & 0xFFFFu) | (ub << 16);
}
__device__ __forceinline__ unsigned short bf16_of(float a) {
  unsigned ua = __builtin_bit_cast(unsigned, a);
  return (unsigned short)((ua + 0x7FFFu + ((ua >> 16) & 1u)) >> 16);
}
__device__ __forceinline__ float f_of_bf16(unsigned short s) {
  return __builtin_bit_cast(float, (unsigned)s << 16);
}
__device__ __forceinline__ unsigned short* state_slot(unsigned short* lo,
                                                      unsigned short* hi,
                                                      int bh, int c) {
  int i = bh * NCHUNK + c;
  return (i < 2048) ? lo + (size_t)i * 8192 : hi + (size_t)(i - 2048) * 8192;
}

// Merged fp32->bf16 casts for {u, in_proj_w, out_proj_w}; 4 elems/thread.
static constexpr int CT1 = NROWS * DMODEL / 4;                 // 2,097,152
static constexpr int CT2 = CT1 + DINPROJ * DMODEL / 4;         // 3,219,456
static constexpr int CT3 = CT2 + DMODEL * DINNER / 4;          // 3,743,744
__global__ __launch_bounds__(256) void cast3_kernel(
    const float* __restrict__ u, const float* __restrict__ w1,
    const float* __restrict__ w2, unsigned short* __restrict__ ub,
    unsigned short* __restrict__ w1b, unsigned short* __restrict__ w2b) {
  int i = blockIdx.x * 256 + threadIdx.x;
  const float* src;
  unsigned short* dst;
  int off;
  if (i < CT1) {
    src = u; dst = ub; off = i;
  } else if (i < CT2) {
    src = w1; dst = w1b; off = i - CT1;
  } else {
    src = w2; dst = w2b; off = i - CT2;
  }
  float4 v = ((const float4*)src)[off];
  ((uint2*)dst)[off] = make_uint2(pk_bf16(v.x, v.y), pk_bf16(v.z, v.w));
}

// ---------------------------------------------------------------------------
// BMx256 pipelined GEMM (R5-verified): C[M][N] = A[M][K] * Bw[N][K]^T, bf16.
// 512 thr = 8 waves (2M x 4N), per-wave C = (BM/2) x 64 (acc[MI][4]).
// K in 32-wide slices through a 4-slot LDS ring (one [BM+256][32] region/slot).
// Per slice iteration (m201-style phase):
//   { READF(s) (12 ds_read_b128) | stage(s+3) (NLD gloads) | s_barrier
//     | lgkmcnt(0) + sched_barrier | setprio(1) 32 MFMA setprio(0)
//     | WAITVM(2*NLD counted; tail 1*NLD,0,0) | s_barrier }
// T2: 16B-granule XOR swizzle on reads, inverse-applied to the per-lane GLOBAL
// source (linear LDS dest, rule #21).
// T1/L2: 2-level XCD map — XCD x owns m-rows [x*mPerX,(x+1)*mPerX), m-fastest
// within XCD (needs gridDim.y%8==0).
// M % BM == 0; N predicated on store (B rows < NT*256 must be readable).
// ---------------------------------------------------------------------------
#define WAITVM(N) asm volatile("s_waitcnt vmcnt(" #N ")" ::: "memory")

template <int BM, bool C_BF16>
__global__ __launch_bounds__(512, 1) void gemm256_kernel(
    const unsigned short* __restrict__ A, const unsigned short* __restrict__ Bw,
    void* __restrict__ Cp, int M, int N, int K, int lda, int ldb, int ldc) {
  (void)M;
  constexpr int MI = BM / 32;
  constexpr int TOTROWS = BM + 256;
  constexpr int RPW = TOTROWS / 8;
  constexpr int NLD = RPW / 16;
  __shared__ unsigned short sAB[4 * TOTROWS * 32];
  const int tid = threadIdx.x;
  const int w = tid >> 6;
  const int lane = tid & 63;
  const int quad = lane >> 4;
  const int r15 = lane & 15;

  const int NT = gridDim.x;
  const int orig = blockIdx.y * NT + blockIdx.x;
  const int xcd = orig & 7;
  const int loc = orig >> 3;
  const int mPerX = gridDim.y >> 3;
  const int m0 = (xcd * mPerX + (loc % mPerX)) * BM;
  const int n0 = (loc / mPerX) * 256;

  const int wm = w >> 2;
  const int wn = w & 3;

  const unsigned short* gsrc[NLD];
  int lofs[NLD];
#pragma unroll
  for (int ld = 0; ld < NLD; ++ld) {
    int r16 = w * RPW + ld * 16;
    int row = r16 + (lane >> 2);
    int ca = ((lane & 3) ^ ((row >> 1) & 3)) * 8;
    gsrc[ld] = (r16 < BM) ? A + (size_t)(m0 + row) * lda + ca
                          : Bw + (size_t)(n0 + row - BM) * ldb + ca;
    lofs[ld] = r16 * 32;
  }
  const int nslice = K >> 5;

  f32x4 acc[MI][4];
#pragma unroll
  for (int i = 0; i < MI; ++i)
#pragma unroll
    for (int j = 0; j < 4; ++j) acc[i][j] = f32x4{0.f, 0.f, 0.f, 0.f};

  auto ldsAB = (__attribute__((address_space(3))) unsigned short*)sAB;

  auto stage = [&](int ks) {
    const int so = (ks & 3) * (TOTROWS * 32);
#pragma unroll
    for (int ld = 0; ld < NLD; ++ld)
      __builtin_amdgcn_global_load_lds(
          (const __attribute__((address_space(1))) void*)(gsrc[ld] + (size_t)ks * 32),
          (__attribute__((address_space(3))) void*)(ldsAB + so + lofs[ld]), 16, 0, 0);
  };

  const int kx = (quad ^ ((r15 >> 1) & 3)) * 8;

  bf16x8 af[MI], bf[4];

#define READF(S)                                                                \
  {                                                                             \
    const int so_ = ((S) & 3) * (TOTROWS * 32);                                 \
    _Pragma("unroll") for (int i = 0; i < MI; ++i)                              \
        af[i] = *(const bf16x8*)&sAB[so_ + (wm * (BM / 2) + i * 16 + r15) * 32 + kx]; \
    _Pragma("unroll") for (int j = 0; j < 4; ++j)                               \
        bf[j] = *(const bf16x8*)&sAB[so_ + (BM + wn * 64 + j * 16 + r15) * 32 + kx];  \
  }
#define MFMAC()                                                                 \
  _Pragma("unroll") for (int i = 0; i < MI; ++i)                                \
      _Pragma("unroll") for (int j = 0; j < 4; ++j)                             \
          acc[i][j] = __builtin_amdgcn_mfma_f32_16x16x32_bf16(af[i], bf[j],     \
                                                              acc[i][j], 0, 0, 0);

#define WVM_STEADY do { if constexpr (NLD == 4) WAITVM(8); else WAITVM(6); } while (0)
#define WVM_TAIL1  do { if constexpr (NLD == 4) WAITVM(4); else WAITVM(3); } while (0)

  stage(0);
  stage(1);
  stage(2);
  WVM_STEADY;
  __builtin_amdgcn_s_barrier();
  __builtin_amdgcn_sched_barrier(0);

#define GITER(STAGE_STMT, WVM_STMT)                                             \
  {                                                                             \
    READF(s);                                                                   \
    STAGE_STMT;                                                                 \
    __builtin_amdgcn_s_barrier();                                               \
    asm volatile("s_waitcnt lgkmcnt(0)" ::: "memory");                          \
    __builtin_amdgcn_sched_barrier(0);                                          \
    __builtin_amdgcn_s_setprio(1);                                              \
    MFMAC();                                                                    \
    __builtin_amdgcn_s_setprio(0);                                              \
    WVM_STMT;                                                                   \
    __builtin_amdgcn_s_barrier();                                               \
    __builtin_amdgcn_sched_barrier(0);                                          \
  }

  int s = 0;
  for (; s < nslice - 3; ++s) GITER(stage(s + 3), WVM_STEADY);
  GITER((void)0, WVM_TAIL1);
  ++s;
  GITER((void)0, WAITVM(0));
  ++s;
  GITER((void)0, WAITVM(0));
#undef GITER
#undef WVM_STEADY
#undef WVM_TAIL1
#undef MFMAC
#undef READF

  const int rq = quad * 4;
#pragma unroll
  for (int i = 0; i < MI; ++i) {
#pragma unroll
    for (int j = 0; j < 4; ++j) {
      int gcol = n0 + wn * 64 + j * 16 + r15;
      if (gcol < N) {
#pragma unroll
        for (int r = 0; r < 4; ++r) {
          size_t grow = (size_t)(m0 + wm * (BM / 2) + i * 16 + rq + r);
          if constexpr (C_BF16)
            ((unsigned short*)Cp)[grow * (size_t)ldc + gcol] = bf16_of(acc[i][j][r]);
          else
            ((float*)Cp)[grow * (size_t)ldc + gcol] = acc[i][j][r];
        }
      }
    }
  }
}

// conv(D_CONV=4) + bias + SiLU, with dt (softplus) fused into block-col 8.
// bf16 in (zxb cols [2048,4352)), bf16 out; dtv f32 out.
__global__ __launch_bounds__(256) void convdt_kernel(const unsigned short* __restrict__ zx,
                                                     const float* __restrict__ conv_w,
                                                     const float* __restrict__ conv_b,
                                                     const float* __restrict__ dt_bias,
                                                     unsigned short* __restrict__ xbc,
                                                     float* __restrict__ dtv) {
  int c = blockIdx.x * 256 + threadIdx.x;  // 9*256 == CONVDIM
  int row = blockIdx.y;
  int l = row & (L_ - 1);
  float acc = conv_b[c];
#pragma unroll
  for (int k = 0; k < 4; ++k) {
    int ll = l + k - 3;
    if (ll >= 0)
      acc = fmaf(f_of_bf16(zx[(size_t)(row + k - 3) * DINPROJ + DINNER + c]),
                 conv_w[c * 4 + k], acc);
  }
  acc = acc / (1.f + __expf(-acc));
  xbc[(size_t)row * CONVDIM + c] = bf16_of(acc);
  if (blockIdx.x == 8 && threadIdx.x < NH) {
    int hh = threadIdx.x;
    float x = f_of_bf16(zx[(size_t)row * DINPROJ + DINNER + CONVDIM + hh]) + dt_bias[hh];
    dtv[(size_t)row * NH + hh] = (x > 20.f) ? x : log1pf(__expf(x));
  }
}

// ---- SSD pass A: per (b,chunk,head) block. Local Y (+D*x) in place over the
// x-region of xbc; chunk state S_c -> state slot (bf16 [p][n], 64x128).
__global__ __launch_bounds__(256) void ssd_passA(unsigned short* __restrict__ xbc,
                                                 const float* __restrict__ dtv,
                                                 const float* __restrict__ A_log,
                                                 const float* __restrict__ Dvec,
                                                 unsigned short* __restrict__ st_lo,
                                                 unsigned short* __restrict__ st_hi) {
  const int bid = blockIdx.x;          // ((b*32 + c)*32 + h)
  const int h = bid & 31;
  const int c = (bid >> 5) & 31;
  const int b = bid >> 10;
  const int bh = b * 32 + h;
  const int tid = threadIdx.x;
  const int w = tid >> 6;
  const int lane = tid & 63;
  const int quad = lane >> 4;
  const int c15 = lane & 15;

  __shared__ unsigned short sXt[64 * 72];   // X^T [p][t]
  __shared__ unsigned short sBq[64 * 136];  // B [s][n] stride 136; S~ alias stride 72
  __shared__ unsigned short sCB[128 * 72];  // C [t][n] stride 136 / BtT [n][s] stride 72
  __shared__ float sdt[64], scs[64], sg[64];

  const float A = -__expf(A_log[h]);
  const float Dh = Dvec[h];
  const int r0 = b * L_ + c * Q_;

  if (w == 0) {
    float v = dtv[(size_t)(r0 + lane) * NH + h];
    sdt[lane] = v;
    float s = v;
#pragma unroll
    for (int off = 1; off < 64; off <<= 1) {
      float t = __shfl_up(s, off, 64);
      if (lane >= off) s += t;
    }
    scs[lane] = s;
    float T = __shfl(s, 63, 64);
    sg[lane] = __expf(A * (T - s)) * v;
  }
  for (int e = tid; e < 512; e += 256) {   // Xt transpose (conflict-free b16 writes)
    int t = e & 63, pb = e >> 6;
    uint4 v = *(const uint4*)&xbc[(size_t)(r0 + t) * CONVDIM + h * 64 + pb * 8];
    const unsigned short* sv = (const unsigned short*)&v;
#pragma unroll
    for (int j = 0; j < 8; ++j) sXt[(pb * 8 + j) * 72 + t] = sv[j];
  }
  for (int e = tid; e < 1024; e += 256) {  // B, C coalesced dwordx4
    int s = e >> 4, ch = e & 15;
    size_t roff = (size_t)(r0 + s) * CONVDIM + DINNER;
    *(uint4*)&sBq[s * 136 + ch * 8] = *(const uint4*)&xbc[roff + ch * 8];
    *(uint4*)&sCB[s * 136 + ch * 8] = *(const uint4*)&xbc[roff + DSTATE + ch * 8];
  }
  __syncthreads();  // B1

  const int wt = w >> 1, wx = w & 1;
  // S = C @ B^T (K=128)
  f32x4 sacc[2][2];
#pragma unroll
  for (int i = 0; i < 2; ++i)
#pragma unroll
    for (int j = 0; j < 2; ++j) sacc[i][j] = f32x4{0.f, 0.f, 0.f, 0.f};
#pragma unroll
  for (int kk = 0; kk < 4; ++kk) {
    int k8 = quad * 8 + kk * 32;
    bf16x8 a0 = *(const bf16x8*)&sCB[(wt * 32 + c15) * 136 + k8];
    bf16x8 a1 = *(const bf16x8*)&sCB[(wt * 32 + 16 + c15) * 136 + k8];
    bf16x8 b0 = *(const bf16x8*)&sBq[(wx * 32 + c15) * 136 + k8];
    bf16x8 b1 = *(const bf16x8*)&sBq[(wx * 32 + 16 + c15) * 136 + k8];
    sacc[0][0] = __builtin_amdgcn_mfma_f32_16x16x32_bf16(a0, b0, sacc[0][0], 0, 0, 0);
    sacc[0][1] = __builtin_amdgcn_mfma_f32_16x16x32_bf16(a0, b1, sacc[0][1], 0, 0, 0);
    sacc[1][0] = __builtin_amdgcn_mfma_f32_16x16x32_bf16(a1, b0, sacc[1][0], 0, 0, 0);
    sacc[1][1] = __builtin_amdgcn_mfma_f32_16x16x32_bf16(a1, b1, sacc[1][1], 0, 0, 0);
  }
  __syncthreads();  // B2

  // S~ into sBq (stride 72); BtT[n][s] = B[s][n]*g_s into sCB (stride 72, global re-read)
#pragma unroll
  for (int i = 0; i < 2; ++i)
#pragma unroll
    for (int j = 0; j < 2; ++j) {
      int scol = wx * 32 + j * 16 + c15;
      float css = scs[scol], dts = sdt[scol];
#pragma unroll
      for (int r = 0; r < 4; ++r) {
        int trow = wt * 32 + i * 16 + quad * 4 + r;
        float v = (scol <= trow) ? sacc[i][j][r] * __expf(A * (scs[trow] - css)) * dts : 0.f;
        sBq[trow * 72 + scol] = bf16_of(v);
      }
    }
  for (int e = tid; e < 1024; e += 256) {
    int s = e & 63, nb = e >> 6;
    uint4 v = *(const uint4*)&xbc[(size_t)(r0 + s) * CONVDIM + DINNER + nb * 8];
    float g = sg[s];
    const unsigned short* sv = (const unsigned short*)&v;
#pragma unroll
    for (int j = 0; j < 8; ++j)
      sCB[(nb * 8 + j) * 72 + s] = bf16_of(f_of_bf16(sv[j]) * g);
  }
  __syncthreads();  // B3

  // Y_local = S~ @ Xt (K=64), += D*x, bf16 in place over x
  f32x4 yacc[2][2];
#pragma unroll
  for (int i = 0; i < 2; ++i)
#pragma unroll
    for (int j = 0; j < 2; ++j) yacc[i][j] = f32x4{0.f, 0.f, 0.f, 0.f};
#pragma unroll
  for (int kk = 0; kk < 2; ++kk) {
    int k8 = quad * 8 + kk * 32;
    bf16x8 a0 = *(const bf16x8*)&sBq[(wt * 32 + c15) * 72 + k8];
    bf16x8 a1 = *(const bf16x8*)&sBq[(wt * 32 + 16 + c15) * 72 + k8];
    bf16x8 b0 = *(const bf16x8*)&sXt[(wx * 32 + c15) * 72 + k8];
    bf16x8 b1 = *(const bf16x8*)&sXt[(wx * 32 + 16 + c15) * 72 + k8];
    yacc[0][0] = __builtin_amdgcn_mfma_f32_16x16x32_bf16(a0, b0, yacc[0][0], 0, 0, 0);
    yacc[0][1] = __builtin_amdgcn_mfma_f32_16x16x32_bf16(a0, b1, yacc[0][1], 0, 0, 0);
    yacc[1][0] = __builtin_amdgcn_mfma_f32_16x16x32_bf16(a1, b0, yacc[1][0], 0, 0, 0);
    yacc[1][1] = __builtin_amdgcn_mfma_f32_16x16x32_bf16(a1, b1, yacc[1][1], 0, 0, 0);
  }
#pragma unroll
  for (int i = 0; i < 2; ++i)
#pragma unroll
    for (int j = 0; j < 2; ++j) {
      int p = wx * 32 + j * 16 + c15;
#pragma unroll
      for (int r = 0; r < 4; ++r) {
        int t = wt * 32 + i * 16 + quad * 4 + r;
        float xv = f_of_bf16(sXt[p * 72 + t]);
        xbc[(size_t)(r0 + t) * CONVDIM + h * 64 + p] = bf16_of(yacc[i][j][r] + Dh * xv);
      }
    }

  // S_c = Xt @ BtT^T (K=64) -> state slot
  f32x4 hacc[2][4];
#pragma unroll
  for (int i = 0; i < 2; ++i)
#pragma unroll
    for (int j = 0; j < 4; ++j) hacc[i][j] = f32x4{0.f, 0.f, 0.f, 0.f};
  const int wp = w >> 1, wn = w & 1;
#pragma unroll
  for (int kk = 0; kk < 2; ++kk) {
    int k8 = quad * 8 + kk * 32;
    bf16x8 a0 = *(const bf16x8*)&sXt[(wp * 32 + c15) * 72 + k8];
    bf16x8 a1 = *(const bf16x8*)&sXt[(wp * 32 + 16 + c15) * 72 + k8];
    bf16x8 bfr[4];
#pragma unroll
    for (int j = 0; j < 4; ++j)
      bfr[j] = *(const bf16x8*)&sCB[(wn * 64 + j * 16 + c15) * 72 + k8];
#pragma unroll
    for (int j = 0; j < 4; ++j) {
      hacc[0][j] = __builtin_amdgcn_mfma_f32_16x16x32_bf16(a0, bfr[j], hacc[0][j], 0, 0, 0);
      hacc[1][j] = __builtin_amdgcn_mfma_f32_16x16x32_bf16(a1, bfr[j], hacc[1][j], 0, 0, 0);
    }
  }
  unsigned short* slot = state_slot(st_lo, st_hi, bh, c);
#pragma unroll
  for (int i = 0; i < 2; ++i)
#pragma unroll
    for (int j = 0; j < 4; ++j)
#pragma unroll
      for (int r = 0; r < 4; ++r) {
        int p = wp * 32 + i * 16 + quad * 4 + r;
        int n = wn * 64 + j * 16 + c15;
        slot[p * 128 + n] = bf16_of(hacc[i][j][r]);
      }
}

// ---- SSD pass B: h_c = d_c*h_{c-1} + S_c; slot overwritten with h_{c-1}.
// grid 256 = (bh, p-half); thread owns 16 contiguous elems.
__global__ __launch_bounds__(256) void ssd_passB(const float* __restrict__ dtv,
                                                 const float* __restrict__ A_log,
                                                 unsigned short* __restrict__ st_lo,
                                                 unsigned short* __restrict__ st_hi) {
  const int bh = blockIdx.x >> 1;
  const int ph = blockIdx.x & 1;
  const int h = bh & 31;
  const int b = bh >> 5;
  const int tid = threadIdx.x;
  __shared__ float sd[NCHUNK];
  const float A = -__expf(A_log[h]);
  if (tid < NCHUNK) {
    float s = 0.f;
    const float* dp = dtv + (size_t)(b * L_ + tid * Q_) * NH + h;
    for (int i = 0; i < Q_; ++i) s += dp[(size_t)i * NH];
    sd[tid] = __expf(A * s);
  }
  __syncthreads();
  float hreg[16];
#pragma unroll
  for (int k = 0; k < 16; ++k) hreg[k] = 0.f;
  const size_t eoff = (size_t)ph * 4096 + (size_t)tid * 16;
  for (int c = 0; c < NCHUNK; ++c) {
    unsigned short* sp = state_slot(st_lo, st_hi, bh, c) + eoff;
    uint4 t0 = ((const uint4*)sp)[0];
    uint4 t1 = ((const uint4*)sp)[1];
    unsigned o[8];
#pragma unroll
    for (int k = 0; k < 8; ++k) o[k] = pk_bf16(hreg[2 * k], hreg[2 * k + 1]);
    ((uint4*)sp)[0] = make_uint4(o[0], o[1], o[2], o[3]);
    ((uint4*)sp)[1] = make_uint4(o[4], o[5], o[6], o[7]);
    float d = sd[c];
    const unsigned short* tv0 = (const unsigned short*)&t0;
    const unsigned short* tv1 = (const unsigned short*)&t1;
#pragma unroll
    for (int k = 0; k < 8; ++k) hreg[k] = d * hreg[k] + f_of_bf16(tv0[k]);
#pragma unroll
    for (int k = 0; k < 8; ++k) hreg[8 + k] = d * hreg[8 + k] + f_of_bf16(tv1[k]);
  }
}

// ---- SSD pass C: Y += exp(A*cs_t) * (C @ h_prev^T); RMW on xbc x-region.
__global__ __launch_bounds__(256) void ssd_passC(unsigned short* __restrict__ xbc,
                                                 const float* __restrict__ dtv,
                                                 const float* __restrict__ A_log,
                                                 const unsigned short* __restrict__ st_lo,
                                                 const unsigned short* __restrict__ st_hi) {
  const int bid = blockIdx.x;
  const int h = bid & 31;
  const int c = (bid >> 5) & 31;
  const int b = bid >> 10;
  const int bh = b * 32 + h;
  const int tid = threadIdx.x;
  const int w = tid >> 6;
  const int lane = tid & 63;
  const int quad = lane >> 4;
  const int c15 = lane & 15;

  __shared__ unsigned short sC[64 * 136];
  __shared__ unsigned short sH[64 * 136];
  __shared__ float srt[64];

  const float A = -__expf(A_log[h]);
  const int r0 = b * L_ + c * Q_;

  if (w == 0) {
    float v = dtv[(size_t)(r0 + lane) * NH + h];
    float s = v;
#pragma unroll
    for (int off = 1; off < 64; off <<= 1) {
      float t = __shfl_up(s, off, 64);
      if (lane >= off) s += t;
    }
    srt[lane] = __expf(A * s);
  }
  const unsigned short* slot =
      state_slot((unsigned short*)st_lo, (unsigned short*)st_hi, bh, c);
  for (int e = tid; e < 1024; e += 256) {
    int s = e >> 4, ch = e & 15;
    *(uint4*)&sC[s * 136 + ch * 8] =
        *(const uint4*)&xbc[(size_t)(r0 + s) * CONVDIM + DINNER + DSTATE + ch * 8];
    *(uint4*)&sH[s * 136 + ch * 8] = *(const uint4*)&slot[s * 128 + ch * 8];
  }
  __syncthreads();

  const int wt = w >> 1, wx = w & 1;
  f32x4 yacc[2][2];
#pragma unroll
  for (int i = 0; i < 2; ++i)
#pragma unroll
    for (int j = 0; j < 2; ++j) yacc[i][j] = f32x4{0.f, 0.f, 0.f, 0.f};
#pragma unroll
  for (int kk = 0; kk < 4; ++kk) {
    int k8 = quad * 8 + kk * 32;
    bf16x8 a0 = *(const bf16x8*)&sC[(wt * 32 + c15) * 136 + k8];
    bf16x8 a1 = *(const bf16x8*)&sC[(wt * 32 + 16 + c15) * 136 + k8];
    bf16x8 b0 = *(const bf16x8*)&sH[(wx * 32 + c15) * 136 + k8];
    bf16x8 b1 = *(const bf16x8*)&sH[(wx * 32 + 16 + c15) * 136 + k8];
    yacc[0][0] = __builtin_amdgcn_mfma_f32_16x16x32_bf16(a0, b0, yacc[0][0], 0, 0, 0);
    yacc[0][1] = __builtin_amdgcn_mfma_f32_16x16x32_bf16(a0, b1, yacc[0][1], 0, 0, 0);
    yacc[1][0] = __builtin_amdgcn_mfma_f32_16x16x32_bf16(a1, b0, yacc[1][0], 0, 0, 0);
    yacc[1][1] = __builtin_amdgcn_mfma_f32_16x16x32_bf16(a1, b1, yacc[1][1], 0, 0, 0);
  }
#pragma unroll
  for (int i = 0; i < 2; ++i)
#pragma unroll
    for (int j = 0; j < 2; ++j) {
      int p = wx * 32 + j * 16 + c15;
#pragma unroll
      for (int r = 0; r < 4; ++r) {
        int t = wt * 32 + i * 16 + quad * 4 + r;
        size_t ga = (size_t)(r0 + t) * CONVDIM + h * 64 + p;
        float v = yacc[i][j][r] * srt[t] + f_of_bf16(xbc[ga]);
        xbc[ga] = bf16_of(v);
      }
    }
}

// gate + RMSNorm; y bf16 from xbc, z bf16 from zxb; out bf16 into z-region.
__global__ __launch_bounds__(256) void norm_kernel(const unsigned short* __restrict__ y_in,
                                                   unsigned short* __restrict__ zxb,
                                                   const float* __restrict__ norm_w) {
  const int row = blockIdx.x;
  const int tid = threadIdx.x;
  float v[8];
  float ss = 0.f;
#pragma unroll
  for (int i = 0; i < 8; ++i) {
    int c = tid + i * 256;
    float yv = f_of_bf16(y_in[(size_t)row * CONVDIM + c]);
    float z = f_of_bf16(zxb[(size_t)row * DINPROJ + c]);
    yv *= z / (1.f + __expf(-z));
    v[i] = yv;
    ss = fmaf(yv, yv, ss);
  }
#pragma unroll
  for (int o = 32; o > 0; o >>= 1) ss += __shfl_down(ss, o, 64);
  __shared__ float sred[4];
  if ((tid & 63) == 0) sred[tid >> 6] = ss;
  __syncthreads();
  float tot = (sred[0] + sred[1]) + (sred[2] + sred[3]);
  float r = rsqrtf(tot * (1.f / (float)DINNER) + 1e-5f);
#pragma unroll
  for (int i = 0; i < 8; ++i) {
    int c = tid + i * 256;
    zxb[(size_t)row * DINPROJ + c] = bf16_of(v[i] * r * norm_w[c]);
  }
}

extern "C" void kernel_launch(void* const* d_in, const int* in_sizes, int n_in,
                              void* d_out, int out_size, void* d_ws, size_t ws_size,
                              hipStream_t stream) {
  (void)in_sizes; (void)n_in; (void)out_size;
  const float* u          = (const float*)d_in[0];
  const float* in_proj_w  = (const float*)d_in[3];
  const float* conv_w     = (const float*)d_in[4];
  const float* conv_b     = (const float*)d_in[5];
  const float* dt_bias    = (const float*)d_in[6];
  const float* A_log      = (const float*)d_in[7];
  const float* Dvec       = (const float*)d_in[8];
  const float* norm_w     = (const float*)d_in[9];
  const float* out_proj_w = (const float*)d_in[10];
  float* out = (float*)d_out;

  constexpr size_t SZ_ZX   = (size_t)NROWS * DINPROJ * 2;   // 71,827,456
  constexpr size_t SZ_XBC  = (size_t)NROWS * CONVDIM * 2;   // 37,748,736
  constexpr size_t SZ_DT   = (size_t)NROWS * NH * 4;        //  1,048,576
  constexpr size_t SZ_SHR  = 33554432;                      // casts, later states-hi
  constexpr size_t SZ_WOUT = (size_t)DMODEL * DINNER * 2;   //  4,194,304
  constexpr size_t NEED = SZ_ZX + SZ_XBC + SZ_DT + SZ_SHR + SZ_WOUT;  // 148,373,504
  if (ws_size < NEED) return;

  char* p = (char*)d_ws;
  unsigned short* zxb  = (unsigned short*)p; p += SZ_ZX;
  unsigned short* xbc  = (unsigned short*)p; p += SZ_XBC;
  float* dtv           = (float*)p;          p += SZ_DT;
  char* shared_reg     = p;                  p += SZ_SHR;
  unsigned short* wout_bf = (unsigned short*)p;

  unsigned short* u_bf   = (unsigned short*)shared_reg;                 // 16.8MB
  unsigned short* win_bf = (unsigned short*)(shared_reg + 16777216);    // 9.0MB + slack
  unsigned short* st_lo  = (unsigned short*)d_out;                      // 2048 slots
  unsigned short* st_hi  = (unsigned short*)shared_reg;                 // 2048 slots

  cast3_kernel<<<CT3 / 256, 256, 0, stream>>>(u, in_proj_w, out_proj_w,
                                              u_bf, win_bf, wout_bf);

  // GEMM1: N=4384 via 18 N-tiles of 256 (stores predicated; B-row overreads
  // up to row 4607 stay inside the shared_reg slack past win_bf).
  gemm256_kernel<256, true><<<dim3(18, 32), 512, 0, stream>>>(
      u_bf, win_bf, zxb, NROWS, DINPROJ, DMODEL, DMODEL, DMODEL, DINPROJ);
  convdt_kernel<<<dim3(9, NROWS), 256, 0, stream>>>(zxb, conv_w, conv_b,
                                                    dt_bias, xbc, dtv);

  ssd_passA<<<B_ * NCHUNK * NH, 256, 0, stream>>>(xbc, dtv, A_log, Dvec, st_lo, st_hi);
  ssd_passB<<<B_ * NH * 2, 256, 0, stream>>>(dtv, A_log, st_lo, st_hi);
  ssd_passC<<<B_ * NCHUNK * NH, 256, 0, stream>>>(xbc, dtv, A_log, st_lo, st_hi);

  norm_kernel<<<NROWS, 256, 0, stream>>>(xbc, zxb, norm_w);
  // GEMM2: BM=128 -> 64 M-tiles x 4 N-tiles = 256 blocks (full chip).
  gemm256_kernel<128, false><<<dim3(4, 64), 512, 0, stream>>>(
      zxb, wout_bf, out, NROWS, DMODEL, DINNER, DINPROJ, DINNER, DMODEL);
}